// Round 5
// baseline (48912.180 us; speedup 1.0000x reference)
//
#include <hip/hip_runtime.h>
#include <stdint.h>

// Neural-ODE RK4: B=131072 points, 2D state, g(y)=tanh(y@W1+b1)@W2+b2, H=256.
// R5: hidden units split across the 4 WAVES of a block (lane = point).
// Weight addresses stay wave-uniform -> s_load (no VGPR cost, no spills),
// while 4x thread count gives 8 waves/SIMD to fill the trans pipe.
// Cross-wave k-reduction via double-buffered LDS, one barrier per eval.

#define NH 256
#define NPAIR 128
// ws: NPAIR groups of 10 floats (pair-interleaved), then tail.
// group m: {cW1[0][2m],cW1[0][2m+1], cW1[1][2m],cW1[1][2m+1], cb1[2m],cb1[2m+1],
//           -2hW2[2m][0],-2hW2[2m+1][0], -2hW2[2m][1],-2hW2[2m+1][1]}
#define WS_TAIL (10*NPAIR)
#define WS_BASE (WS_TAIL + 0)   // 2 floats: h*(sum_j W2[j][k] + b2[k])
#define WS_WF   (WS_TAIL + 2)   // 4 floats
#define WS_BF   (WS_TAIL + 6)   // 2 floats
#define WS_N    (WS_TAIL + 8)   // 1 int

typedef __attribute__((ext_vector_type(2))) float f32x2;

__device__ __forceinline__ float fexp2(float x) {
#if __has_builtin(__builtin_amdgcn_exp2f)
  return __builtin_amdgcn_exp2f(x);
#else
  return exp2f(x);
#endif
}
__device__ __forceinline__ float frcp(float x) {
#if __has_builtin(__builtin_amdgcn_rcpf)
  return __builtin_amdgcn_rcpf(x);
#else
  return 1.0f / x;
#endif
}
__device__ __forceinline__ f32x2 pk_fma(f32x2 a, f32x2 b, f32x2 c) {
  return __builtin_elementwise_fma(a, b, c);   // v_pk_fma_f32
}

__global__ void prep_kernel(const float* __restrict__ w1,
                            const float* __restrict__ b1,
                            const float* __restrict__ w2,
                            const float* __restrict__ b2,
                            const float* __restrict__ wf,
                            const float* __restrict__ bfv,
                            const int* __restrict__ tptr,
                            float* __restrict__ ws) {
  const float h = 0.01f;
  const float c = 2.88539008177792681f;  // 2*log2(e): tanh(z)=1-2/(exp2(c*z)+1)
  int m = threadIdx.x;                   // pair index
  if (m < NPAIR) {
    int j0 = 2 * m, j1 = 2 * m + 1;
    float* g = ws + 10 * m;
    g[0] = c * w1[j0];        g[1] = c * w1[j1];         // W1[0][j]
    g[2] = c * w1[NH + j0];   g[3] = c * w1[NH + j1];    // W1[1][j]
    g[4] = c * b1[j0];        g[5] = c * b1[j1];
    g[6] = -2.0f * h * w2[2 * j0];      g[7] = -2.0f * h * w2[2 * j1];      // W2[j][0]
    g[8] = -2.0f * h * w2[2 * j0 + 1];  g[9] = -2.0f * h * w2[2 * j1 + 1];  // W2[j][1]
  }
  if (m == 0) {
    float s0 = 0.f, s1 = 0.f;
    for (int k = 0; k < NH; ++k) { s0 += w2[2 * k]; s1 += w2[2 * k + 1]; }
    ws[WS_BASE + 0] = h * (s0 + b2[0]);   // tanh = 1-2u: "+1" term folded here
    ws[WS_BASE + 1] = h * (s1 + b2[1]);
    ws[WS_WF + 0] = wf[0]; ws[WS_WF + 1] = wf[1];
    ws[WS_WF + 2] = wf[2]; ws[WS_WF + 3] = wf[3];
    ws[WS_BF + 0] = bfv[0]; ws[WS_BF + 1] = bfv[1];
    // Python: n,t=0,0.0; while t <= tf: n+=1; t+=0.01 (float64 accumulation)
    double tf = 0.1 * (double)tptr[0];
    double tt = 0.0; int n = 0;
    while (tt <= tf) { n++; tt += 0.01; }
    ((int*)ws)[WS_N] = n;
  }
}

#define BATCH 4
// Partial over this wave's 32 pairs; wq is wave-uniform -> s_load weights.
__device__ __forceinline__ void gh_partial(const float* __restrict__ wq,
                                           float u0, float u1,
                                           float& p0, float& p1) {
  f32x2 u0v = {u0, u0}, u1v = {u1, u1};
  f32x2 acc0 = {0.0f, 0.0f};
  f32x2 acc1 = {0.0f, 0.0f};
  for (int b = 0; b < 32 / BATCH; ++b) {
    const f32x2* g = (const f32x2*)(wq + 10 * BATCH * b);
    f32x2 z[BATCH], r[BATCH];
#pragma unroll
    for (int m = 0; m < BATCH; ++m)
      z[m] = pk_fma(u0v, g[5 * m + 0], pk_fma(u1v, g[5 * m + 1], g[5 * m + 2]));
#pragma unroll
    for (int m = 0; m < BATCH; ++m) {
      f32x2 e;
      e.x = fexp2(z[m].x); e.y = fexp2(z[m].y);
      e = e + 1.0f;
      r[m].x = frcp(e.x); r[m].y = frcp(e.y);
    }
#pragma unroll
    for (int m = 0; m < BATCH; ++m) {
      acc0 = pk_fma(g[5 * m + 3], r[m], acc0);
      acc1 = pk_fma(g[5 * m + 4], r[m], acc1);
    }
  }
  p0 = acc0.x + acc0.y;
  p1 = acc1.x + acc1.y;
}

__global__ __launch_bounds__(256, 8) void ode_kernel(const float2* __restrict__ x,
                                                     const float* __restrict__ ws,
                                                     float2* __restrict__ out,
                                                     int npts) {
  // double-buffered cross-wave reduction scratch: [buf][wave][lane]
  __shared__ float red0[2][4][64];
  __shared__ float red1[2][4][64];

  int lane = threadIdx.x & 63;
  int w    = threadIdx.x >> 6;             // wave id = j-quarter
  int pt   = blockIdx.x * 64 + lane;
  if (pt >= npts) pt = npts - 1;           // clamp (keeps barriers uniform)

  float2 xi = x[pt];
  float y0 = xi.x, y1 = xi.y;

  const float* wq = ws + 320 * w;          // wave-uniform -> scalar loads
  const float base0 = ws[WS_BASE + 0];
  const float base1 = ws[WS_BASE + 1];
  const int n = ((const int*)ws)[WS_N];

  int buf = 0;
  // one eval of h*g(y): partial over this wave's quarter, then LDS-reduce.
  auto gh = [&](float u0, float u1, float& k0, float& k1) {
    float p0, p1;
    gh_partial(wq, u0, u1, p0, p1);
    red0[buf][w][lane] = p0;
    red1[buf][w][lane] = p1;
    __syncthreads();
    float s0 = base0, s1 = base1;
#pragma unroll
    for (int ww = 0; ww < 4; ++ww) {
      s0 += red0[buf][ww][lane];
      s1 += red1[buf][ww][lane];
    }
    buf ^= 1;   // safe: one barrier separates reuse of each buffer
    k0 = s0; k1 = s1;
  };

  for (int s = 0; s < n; ++s) {
    float k10, k11, k20, k21, k30, k31, k40, k41;
    gh(y0, y1, k10, k11);
    gh(fmaf(0.5f, k10, y0), fmaf(0.5f, k11, y1), k20, k21);
    gh(fmaf(0.5f, k20, y0), fmaf(0.5f, k21, y1), k30, k31);
    gh(y0 + k30, y1 + k31, k40, k41);
    y0 += (k10 + 2.0f * (k20 + k30) + k40) * (1.0f / 6.0f);
    y1 += (k11 + 2.0f * (k21 + k31) + k41) * (1.0f / 6.0f);
  }

  if (w == 0) {
    float wf00 = ws[WS_WF + 0], wf01 = ws[WS_WF + 1];
    float wf10 = ws[WS_WF + 2], wf11 = ws[WS_WF + 3];
    float l0 = fmaf(y0, wf00, fmaf(y1, wf10, ws[WS_BF + 0]));
    float l1 = fmaf(y0, wf01, fmaf(y1, wf11, ws[WS_BF + 1]));

    float m = fmaxf(l0, l1);
    const float log2e = 1.44269504088896340f;
    float e0 = fexp2((l0 - m) * log2e);
    float e1 = fexp2((l1 - m) * log2e);
    float inv = frcp(e0 + e1);

    out[pt]        = make_float2(l0, l1);
    out[npts + pt] = make_float2(e0 * inv, e1 * inv);
  }
}

extern "C" void kernel_launch(void* const* d_in, const int* in_sizes, int n_in,
                              void* d_out, int out_size, void* d_ws, size_t ws_size,
                              hipStream_t stream) {
  const float* x   = (const float*)d_in[0];
  const float* w1  = (const float*)d_in[1];
  const float* b1  = (const float*)d_in[2];
  const float* w2  = (const float*)d_in[3];
  const float* b2  = (const float*)d_in[4];
  const float* wf  = (const float*)d_in[5];
  const float* bfv = (const float*)d_in[6];
  const int* tptr  = (const int*)d_in[7];
  float* ws = (float*)d_ws;

  int npts = in_sizes[0] / 2;  // 131072
  int nblocks = (npts + 63) / 64;

  prep_kernel<<<1, 256, 0, stream>>>(w1, b1, w2, b2, wf, bfv, tptr, ws);
  ode_kernel<<<nblocks, 256, 0, stream>>>(
      (const float2*)x, ws, (float2*)d_out, npts);
}

// Round 6
// 5733.097 us; speedup vs baseline: 8.5315x; 8.5315x over previous
//
#include <hip/hip_runtime.h>
#include <stdint.h>

// Neural-ODE RK4: B=131072 points, 2D state, g(y)=tanh(y@W1+b1)@W2+b2, H=256.
// R6: R5 wave-split structure + readfirstlane on the wave id so the weight
// pointer is PROVABLY uniform -> s_load through K$ (R5's fatal flaw was this
// demoting to per-lane VMEM: FETCH 124 GB, 48.9 ms). 4 waves/block own the
// 4 j-quarters; lane = point; cross-wave reduce via double-buffered LDS.
// 8 waves/SIMD fill the quarter-rate transcendental pipe across waves.

#define NH 256
#define NPAIR 128
// ws: NPAIR groups of 10 floats (pair-interleaved), then tail.
// group m: {cW1[0][2m],cW1[0][2m+1], cW1[1][2m],cW1[1][2m+1], cb1[2m],cb1[2m+1],
//           -2hW2[2m][0],-2hW2[2m+1][0], -2hW2[2m][1],-2hW2[2m+1][1]}
#define WS_TAIL (10*NPAIR)
#define WS_BASE (WS_TAIL + 0)   // 2 floats: h*(sum_j W2[j][k] + b2[k])
#define WS_WF   (WS_TAIL + 2)   // 4 floats
#define WS_BF   (WS_TAIL + 6)   // 2 floats
#define WS_N    (WS_TAIL + 8)   // 1 int

typedef __attribute__((ext_vector_type(2))) float f32x2;

__device__ __forceinline__ float fexp2(float x) {
#if __has_builtin(__builtin_amdgcn_exp2f)
  return __builtin_amdgcn_exp2f(x);
#else
  return exp2f(x);
#endif
}
__device__ __forceinline__ float frcp(float x) {
#if __has_builtin(__builtin_amdgcn_rcpf)
  return __builtin_amdgcn_rcpf(x);
#else
  return 1.0f / x;
#endif
}
__device__ __forceinline__ f32x2 pk_fma(f32x2 a, f32x2 b, f32x2 c) {
  return __builtin_elementwise_fma(a, b, c);   // v_pk_fma_f32
}

__global__ void prep_kernel(const float* __restrict__ w1,
                            const float* __restrict__ b1,
                            const float* __restrict__ w2,
                            const float* __restrict__ b2,
                            const float* __restrict__ wf,
                            const float* __restrict__ bfv,
                            const int* __restrict__ tptr,
                            float* __restrict__ ws) {
  const float h = 0.01f;
  const float c = 2.88539008177792681f;  // 2*log2(e): tanh(z)=1-2/(exp2(c*z)+1)
  int m = threadIdx.x;                   // pair index
  if (m < NPAIR) {
    int j0 = 2 * m, j1 = 2 * m + 1;
    float* g = ws + 10 * m;
    g[0] = c * w1[j0];        g[1] = c * w1[j1];         // W1[0][j]
    g[2] = c * w1[NH + j0];   g[3] = c * w1[NH + j1];    // W1[1][j]
    g[4] = c * b1[j0];        g[5] = c * b1[j1];
    g[6] = -2.0f * h * w2[2 * j0];      g[7] = -2.0f * h * w2[2 * j1];      // W2[j][0]
    g[8] = -2.0f * h * w2[2 * j0 + 1];  g[9] = -2.0f * h * w2[2 * j1 + 1];  // W2[j][1]
  }
  if (m == 0) {
    float s0 = 0.f, s1 = 0.f;
    for (int k = 0; k < NH; ++k) { s0 += w2[2 * k]; s1 += w2[2 * k + 1]; }
    ws[WS_BASE + 0] = h * (s0 + b2[0]);   // tanh = 1-2u: "+1" term folded here
    ws[WS_BASE + 1] = h * (s1 + b2[1]);
    ws[WS_WF + 0] = wf[0]; ws[WS_WF + 1] = wf[1];
    ws[WS_WF + 2] = wf[2]; ws[WS_WF + 3] = wf[3];
    ws[WS_BF + 0] = bfv[0]; ws[WS_BF + 1] = bfv[1];
    // Python: n,t=0,0.0; while t <= tf: n+=1; t+=0.01 (float64 accumulation)
    double tf = 0.1 * (double)tptr[0];
    double tt = 0.0; int n = 0;
    while (tt <= tf) { n++; tt += 0.01; }
    ((int*)ws)[WS_N] = n;
  }
}

#define BATCH 4
// Partial over this wave's 32 pairs; wq is sgpr-uniform -> s_load weights.
__device__ __forceinline__ void gh_partial(const float* __restrict__ wq,
                                           float u0, float u1,
                                           float& p0, float& p1) {
  f32x2 u0v = {u0, u0}, u1v = {u1, u1};
  f32x2 acc0 = {0.0f, 0.0f};
  f32x2 acc1 = {0.0f, 0.0f};
  for (int b = 0; b < 32 / BATCH; ++b) {
    const f32x2* g = (const f32x2*)(wq + 10 * BATCH * b);
    f32x2 z[BATCH], r[BATCH];
#pragma unroll
    for (int m = 0; m < BATCH; ++m)
      z[m] = pk_fma(u0v, g[5 * m + 0], pk_fma(u1v, g[5 * m + 1], g[5 * m + 2]));
#pragma unroll
    for (int m = 0; m < BATCH; ++m) {
      f32x2 e;
      e.x = fexp2(z[m].x); e.y = fexp2(z[m].y);
      e = e + 1.0f;
      r[m].x = frcp(e.x); r[m].y = frcp(e.y);
    }
#pragma unroll
    for (int m = 0; m < BATCH; ++m) {
      acc0 = pk_fma(g[5 * m + 3], r[m], acc0);
      acc1 = pk_fma(g[5 * m + 4], r[m], acc1);
    }
  }
  p0 = acc0.x + acc0.y;
  p1 = acc1.x + acc1.y;
}

__global__ __launch_bounds__(256, 8) void ode_kernel(const float2* __restrict__ x,
                                                     const float* __restrict__ ws,
                                                     float2* __restrict__ out,
                                                     int npts) {
  // double-buffered cross-wave reduction scratch: [buf][wave][lane]
  __shared__ float2 red[2][4][64];

  int lane = threadIdx.x & 63;
  int w    = threadIdx.x >> 6;                 // wave id = j-quarter
  w = __builtin_amdgcn_readfirstlane(w);       // FORCE uniform -> SGPR pointer
  int pt   = blockIdx.x * 64 + lane;
  if (pt >= npts) pt = npts - 1;               // clamp (keeps barriers uniform)

  float2 xi = x[pt];
  float y0 = xi.x, y1 = xi.y;

  const float* wq = ws + 320 * w;              // SGPR base -> s_load weights
  const float base0 = ws[WS_BASE + 0];
  const float base1 = ws[WS_BASE + 1];
  const int n = ((const int*)ws)[WS_N];

  int buf = 0;
  // one eval of h*g(y): partial over this wave's quarter, then LDS-reduce.
  auto gh = [&](float u0, float u1, float& k0, float& k1) {
    float p0, p1;
    gh_partial(wq, u0, u1, p0, p1);
    red[buf][w][lane] = make_float2(p0, p1);
    __syncthreads();
    float s0 = base0, s1 = base1;
#pragma unroll
    for (int ww = 0; ww < 4; ++ww) {
      float2 t = red[buf][ww][lane];
      s0 += t.x; s1 += t.y;
    }
    buf ^= 1;   // safe: one barrier separates reuse of each buffer
    k0 = s0; k1 = s1;
  };

  for (int s = 0; s < n; ++s) {
    float k10, k11, k20, k21, k30, k31, k40, k41;
    gh(y0, y1, k10, k11);
    gh(fmaf(0.5f, k10, y0), fmaf(0.5f, k11, y1), k20, k21);
    gh(fmaf(0.5f, k20, y0), fmaf(0.5f, k21, y1), k30, k31);
    gh(y0 + k30, y1 + k31, k40, k41);
    y0 += (k10 + 2.0f * (k20 + k30) + k40) * (1.0f / 6.0f);
    y1 += (k11 + 2.0f * (k21 + k31) + k41) * (1.0f / 6.0f);
  }

  if (w == 0) {
    float wf00 = ws[WS_WF + 0], wf01 = ws[WS_WF + 1];
    float wf10 = ws[WS_WF + 2], wf11 = ws[WS_WF + 3];
    float l0 = fmaf(y0, wf00, fmaf(y1, wf10, ws[WS_BF + 0]));
    float l1 = fmaf(y0, wf01, fmaf(y1, wf11, ws[WS_BF + 1]));

    float m = fmaxf(l0, l1);
    const float log2e = 1.44269504088896340f;
    float e0 = fexp2((l0 - m) * log2e);
    float e1 = fexp2((l1 - m) * log2e);
    float inv = frcp(e0 + e1);

    out[pt]        = make_float2(l0, l1);
    out[npts + pt] = make_float2(e0 * inv, e1 * inv);
  }
}

extern "C" void kernel_launch(void* const* d_in, const int* in_sizes, int n_in,
                              void* d_out, int out_size, void* d_ws, size_t ws_size,
                              hipStream_t stream) {
  const float* x   = (const float*)d_in[0];
  const float* w1  = (const float*)d_in[1];
  const float* b1  = (const float*)d_in[2];
  const float* w2  = (const float*)d_in[3];
  const float* b2  = (const float*)d_in[4];
  const float* wf  = (const float*)d_in[5];
  const float* bfv = (const float*)d_in[6];
  const int* tptr  = (const int*)d_in[7];
  float* ws = (float*)d_ws;

  int npts = in_sizes[0] / 2;  // 131072
  int nblocks = (npts + 63) / 64;

  prep_kernel<<<1, 256, 0, stream>>>(w1, b1, w2, b2, wf, bfv, tptr, ws);
  ode_kernel<<<nblocks, 256, 0, stream>>>(
      (const float2*)x, ws, (float2*)d_out, npts);
}

// Round 7
// 3047.047 us; speedup vs baseline: 16.0523x; 1.8815x over previous
//
#include <hip/hip_runtime.h>
#include <stdint.h>

// Neural-ODE RK4: B=131072 points, 2D state, g(y)=tanh(y@W1+b1)@W2+b2, H=256.
// R7: 2-way j-split across the 2 waves of a 128-thread block (lane = point).
// - weights SGPR-uniform via readfirstlane (R6-proven: s_load, K$-served)
// - __launch_bounds__(128,4): 128-VGPR budget -> batch arrays stay in regs
//   (R6's fatal flaw: (256,8) -> 32 VGPRs -> 12.8 GB scratch spill traffic)
// - 4 waves/SIMD fills the quarter-rate trans pipe across waves
// - 2-way double-buffered LDS reduction, one barrier per eval

#define NH 256
#define NPAIR 128
// ws: NPAIR groups of 10 floats (pair-interleaved), then tail.
// group m: {cW1[0][2m],cW1[0][2m+1], cW1[1][2m],cW1[1][2m+1], cb1[2m],cb1[2m+1],
//           -2hW2[2m][0],-2hW2[2m+1][0], -2hW2[2m][1],-2hW2[2m+1][1]}
#define WS_TAIL (10*NPAIR)
#define WS_BASE (WS_TAIL + 0)   // 2 floats: h*(sum_j W2[j][k] + b2[k])
#define WS_WF   (WS_TAIL + 2)   // 4 floats
#define WS_BF   (WS_TAIL + 6)   // 2 floats
#define WS_N    (WS_TAIL + 8)   // 1 int

typedef __attribute__((ext_vector_type(2))) float f32x2;

__device__ __forceinline__ float fexp2(float x) {
#if __has_builtin(__builtin_amdgcn_exp2f)
  return __builtin_amdgcn_exp2f(x);
#else
  return exp2f(x);
#endif
}
__device__ __forceinline__ float frcp(float x) {
#if __has_builtin(__builtin_amdgcn_rcpf)
  return __builtin_amdgcn_rcpf(x);
#else
  return 1.0f / x;
#endif
}
__device__ __forceinline__ f32x2 pk_fma(f32x2 a, f32x2 b, f32x2 c) {
  return __builtin_elementwise_fma(a, b, c);   // v_pk_fma_f32
}

__global__ void prep_kernel(const float* __restrict__ w1,
                            const float* __restrict__ b1,
                            const float* __restrict__ w2,
                            const float* __restrict__ b2,
                            const float* __restrict__ wf,
                            const float* __restrict__ bfv,
                            const int* __restrict__ tptr,
                            float* __restrict__ ws) {
  const float h = 0.01f;
  const float c = 2.88539008177792681f;  // 2*log2(e): tanh(z)=1-2/(exp2(c*z)+1)
  int m = threadIdx.x;                   // pair index
  if (m < NPAIR) {
    int j0 = 2 * m, j1 = 2 * m + 1;
    float* g = ws + 10 * m;
    g[0] = c * w1[j0];        g[1] = c * w1[j1];         // W1[0][j]
    g[2] = c * w1[NH + j0];   g[3] = c * w1[NH + j1];    // W1[1][j]
    g[4] = c * b1[j0];        g[5] = c * b1[j1];
    g[6] = -2.0f * h * w2[2 * j0];      g[7] = -2.0f * h * w2[2 * j1];      // W2[j][0]
    g[8] = -2.0f * h * w2[2 * j0 + 1];  g[9] = -2.0f * h * w2[2 * j1 + 1];  // W2[j][1]
  }
  if (m == 0) {
    float s0 = 0.f, s1 = 0.f;
    for (int k = 0; k < NH; ++k) { s0 += w2[2 * k]; s1 += w2[2 * k + 1]; }
    ws[WS_BASE + 0] = h * (s0 + b2[0]);   // tanh = 1-2u: "+1" term folded here
    ws[WS_BASE + 1] = h * (s1 + b2[1]);
    ws[WS_WF + 0] = wf[0]; ws[WS_WF + 1] = wf[1];
    ws[WS_WF + 2] = wf[2]; ws[WS_WF + 3] = wf[3];
    ws[WS_BF + 0] = bfv[0]; ws[WS_BF + 1] = bfv[1];
    // Python: n,t=0,0.0; while t <= tf: n+=1; t+=0.01 (float64 accumulation)
    double tf = 0.1 * (double)tptr[0];
    double tt = 0.0; int n = 0;
    while (tt <= tf) { n++; tt += 0.01; }
    ((int*)ws)[WS_N] = n;
  }
}

#define BATCH 4
// Partial over this wave's 64 pairs; wq is SGPR-uniform -> s_load weights.
__device__ __forceinline__ void gh_partial(const float* __restrict__ wq,
                                           float u0, float u1,
                                           float& p0, float& p1) {
  f32x2 u0v = {u0, u0}, u1v = {u1, u1};
  f32x2 acc0 = {0.0f, 0.0f};
  f32x2 acc1 = {0.0f, 0.0f};
  for (int b = 0; b < 64 / BATCH; ++b) {
    const f32x2* g = (const f32x2*)(wq + 10 * BATCH * b);
    f32x2 z[BATCH], r[BATCH];
#pragma unroll
    for (int m = 0; m < BATCH; ++m)
      z[m] = pk_fma(u0v, g[5 * m + 0], pk_fma(u1v, g[5 * m + 1], g[5 * m + 2]));
#pragma unroll
    for (int m = 0; m < BATCH; ++m) {
      f32x2 e;
      e.x = fexp2(z[m].x); e.y = fexp2(z[m].y);
      e = e + 1.0f;
      r[m].x = frcp(e.x); r[m].y = frcp(e.y);
    }
#pragma unroll
    for (int m = 0; m < BATCH; ++m) {
      acc0 = pk_fma(g[5 * m + 3], r[m], acc0);
      acc1 = pk_fma(g[5 * m + 4], r[m], acc1);
    }
  }
  p0 = acc0.x + acc0.y;
  p1 = acc1.x + acc1.y;
}

__global__ __launch_bounds__(128, 4) void ode_kernel(const float2* __restrict__ x,
                                                     const float* __restrict__ ws,
                                                     float2* __restrict__ out,
                                                     int npts) {
  // double-buffered cross-wave reduction scratch: [buf][wave][lane]
  __shared__ float2 red[2][2][64];

  int lane = threadIdx.x & 63;
  int w    = threadIdx.x >> 6;                 // wave id = j-half
  w = __builtin_amdgcn_readfirstlane(w);       // force SGPR -> s_load weights
  int pt   = blockIdx.x * 64 + lane;
  if (pt >= npts) pt = npts - 1;               // clamp (keeps barriers uniform)

  float2 xi = x[pt];
  float y0 = xi.x, y1 = xi.y;

  const float* wq = ws + 640 * w;              // SGPR base: pairs [64w, 64w+64)
  const float base0 = ws[WS_BASE + 0];
  const float base1 = ws[WS_BASE + 1];
  const int n = ((const int*)ws)[WS_N];

  int buf = 0;
  // one eval of h*g(y): partial over this wave's half, then 2-way LDS reduce.
  auto gh = [&](float u0, float u1, float& k0, float& k1) {
    float p0, p1;
    gh_partial(wq, u0, u1, p0, p1);
    red[buf][w][lane] = make_float2(p0, p1);
    __syncthreads();
    float2 t0 = red[buf][0][lane];
    float2 t1 = red[buf][1][lane];
    buf ^= 1;   // safe: one barrier separates reuse of each buffer
    k0 = base0 + t0.x + t1.x;
    k1 = base1 + t0.y + t1.y;
  };

  for (int s = 0; s < n; ++s) {
    float k10, k11, k20, k21, k30, k31, k40, k41;
    gh(y0, y1, k10, k11);
    gh(fmaf(0.5f, k10, y0), fmaf(0.5f, k11, y1), k20, k21);
    gh(fmaf(0.5f, k20, y0), fmaf(0.5f, k21, y1), k30, k31);
    gh(y0 + k30, y1 + k31, k40, k41);
    y0 += (k10 + 2.0f * (k20 + k30) + k40) * (1.0f / 6.0f);
    y1 += (k11 + 2.0f * (k21 + k31) + k41) * (1.0f / 6.0f);
  }

  if (w == 0) {
    float wf00 = ws[WS_WF + 0], wf01 = ws[WS_WF + 1];
    float wf10 = ws[WS_WF + 2], wf11 = ws[WS_WF + 3];
    float l0 = fmaf(y0, wf00, fmaf(y1, wf10, ws[WS_BF + 0]));
    float l1 = fmaf(y0, wf01, fmaf(y1, wf11, ws[WS_BF + 1]));

    float m = fmaxf(l0, l1);
    const float log2e = 1.44269504088896340f;
    float e0 = fexp2((l0 - m) * log2e);
    float e1 = fexp2((l1 - m) * log2e);
    float inv = frcp(e0 + e1);

    out[pt]        = make_float2(l0, l1);
    out[npts + pt] = make_float2(e0 * inv, e1 * inv);
  }
}

extern "C" void kernel_launch(void* const* d_in, const int* in_sizes, int n_in,
                              void* d_out, int out_size, void* d_ws, size_t ws_size,
                              hipStream_t stream) {
  const float* x   = (const float*)d_in[0];
  const float* w1  = (const float*)d_in[1];
  const float* b1  = (const float*)d_in[2];
  const float* w2  = (const float*)d_in[3];
  const float* b2  = (const float*)d_in[4];
  const float* wf  = (const float*)d_in[5];
  const float* bfv = (const float*)d_in[6];
  const int* tptr  = (const int*)d_in[7];
  float* ws = (float*)d_ws;

  int npts = in_sizes[0] / 2;  // 131072
  int nblocks = (npts + 63) / 64;

  prep_kernel<<<1, 256, 0, stream>>>(w1, b1, w2, b2, wf, bfv, tptr, ws);
  ode_kernel<<<nblocks, 128, 0, stream>>>(
      (const float2*)x, ws, (float2*)d_out, npts);
}